// Round 17
// baseline (205.819 us; speedup 1.0000x reference)
//
#include <hip/hip_runtime.h>
#include <hip/hip_bf16.h>

// Problem constants (B=4, T=2048, D=1024, H=16, HD=64)
constexpr int NB  = 4;
constexpr int NT  = 2048;
constexpr int ND  = 1024;
constexpr int NH  = 16;
constexpr int NHD = 64;
constexpr int NM  = NB * NT;   // 8192 tokens

typedef unsigned short u16;
typedef __attribute__((ext_vector_type(8))) short  short8;  // 8 bf16 (4 VGPRs)
typedef __attribute__((ext_vector_type(4))) float  f32x4;   // MFMA acc

__device__ __forceinline__ u16 f2bf(float f) {
  unsigned u = __builtin_bit_cast(unsigned, f);
  u += 0x7FFFu + ((u >> 16) & 1u);   // round-to-nearest-even
  return (u16)(u >> 16);
}

// pack two f32 -> 2x bf16 in one dword (compiler emits v_cvt_pk_bf16_f32)
__device__ __forceinline__ unsigned pk2bf(float lo, float hi_) {
  float2 t; t.x = lo; t.y = hi_;
  __hip_bfloat162 h2 = __float22bfloat162_rn(t);
  unsigned u;
  __builtin_memcpy(&u, &h2, 4);
  return u;
}

// async global->LDS, 16B per lane. dst must be wave-uniform; lane i lands at dst + i*16B.
__device__ __forceinline__ void gll16(const u16* src, u16* dst) {
  __builtin_amdgcn_global_load_lds(
      (const __attribute__((address_space(1))) void*)src,
      (__attribute__((address_space(3))) void*)dst, 16, 0, 0);
}

// ---------------- fused cast: x (8192 blocks) + 4 weights (1024 blocks each) ----------------
__global__ __launch_bounds__(256) void cast_all(
    const float* __restrict__ x,
    const float* __restrict__ w0, const float* __restrict__ w1,
    const float* __restrict__ w2, const float* __restrict__ w3,
    u16* __restrict__ xb,
    u16* __restrict__ o0, u16* __restrict__ o1,
    u16* __restrict__ o2, u16* __restrict__ o3) {
  const int bid = blockIdx.x;
  const float* in;
  u16* out;
  int i;
  if (bid < 8192) {
    in = x; out = xb; i = bid * 256 + threadIdx.x;
  } else {
    const int z = (bid - 8192) >> 10;
    in  = (z == 0) ? w0 : (z == 1) ? w1 : (z == 2) ? w2 : w3;
    out = (z == 0) ? o0 : (z == 1) ? o1 : (z == 2) ? o2 : o3;
    i = ((bid - 8192) & 1023) * 256 + threadIdx.x;
  }
  float4 v = ((const float4*)in)[i];
  ushort4 o;
  o.x = f2bf(v.x); o.y = f2bf(v.y); o.z = f2bf(v.z); o.w = f2bf(v.w);
  ((ushort4*)out)[i] = o;
}

// ---------------- QKV GEMM: distance-2 triple-buffer pipeline (r14, 82.5us verified) ----------
__global__ __launch_bounds__(512, 2) void gemm_qkv3(
    const u16* __restrict__ xb,
    const u16* __restrict__ wqb, const u16* __restrict__ wkb, const u16* __restrict__ wvb,
    u16* __restrict__ Qb, u16* __restrict__ Kb, u16* __restrict__ VTb) {
  const int z    = blockIdx.z;
  const int row0 = blockIdx.x << 7;
  const int col0 = blockIdx.y << 7;

  const u16* wsel = (z == 0) ? wqb : (z == 1) ? wkb : wvb;
  u16* osel      = (z == 0) ? Qb  : (z == 1) ? Kb  : VTb;
  const float scl = (z == 0) ? 0.125f * 1.44269504f : 1.0f;  // scale+log2e into Q

  const int tid  = threadIdx.x;
  const int lane = tid & 63, wid = tid >> 6;   // 8 waves
  const int wm = wid >> 2, wn = wid & 3;       // 2 x 4 wave grid
  const int li = lane & 15, hi = lane >> 4;
  const int l3 = lane >> 3, sl = lane & 7;
  const int schunk = ((sl ^ l3) << 3);         // pre-swizzled source chunk (row&7 == l3)

  extern __shared__ __align__(16) u16 smem[];  // 96 KB: 3 x (A 16KB + B 16KB)
  u16* lAb = smem;                              // [3][128*64]
  u16* lBb = smem + 3 * 128 * 64;               // [3][128*64]

  auto stage = [&](int t) {
    const int bo = (t % 3) * 8192;
    const int k0 = t << 6;
#pragma unroll
    for (int h = 0; h < 2; ++h) {
      int r = h * 64 + wid * 8;
      gll16(&xb  [(size_t)(row0 + r + l3) * ND + k0 + schunk], &lAb[bo + r * 64]);
      gll16(&wsel[(size_t)(col0 + r + l3) * ND + k0 + schunk], &lBb[bo + r * 64]);
    }
  };

  f32x4 acc[4][2] = {};

  stage(0);
  stage(1);

  for (int i = 0; i < 16; ++i) {
    if (i < 15) { asm volatile("s_waitcnt vmcnt(4)" ::: "memory"); }
    else        { asm volatile("s_waitcnt vmcnt(0)" ::: "memory"); }
    __builtin_amdgcn_s_barrier();

    if (i + 2 < 16) stage(i + 2);

    const u16* la = &lAb[(i % 3) * 8192];
    const u16* lb = &lBb[(i % 3) * 8192];

    short8 a[4][2], b[2][2];
#pragma unroll
    for (int m = 0; m < 4; ++m)
#pragma unroll
      for (int c = 0; c < 2; ++c)
        a[m][c] = *(const short8*)&la[(wm * 64 + m * 16 + li) * 64 + (((c * 4 + hi) ^ (li & 7)) << 3)];
#pragma unroll
    for (int n = 0; n < 2; ++n)
#pragma unroll
      for (int c = 0; c < 2; ++c)
        b[n][c] = *(const short8*)&lb[(wn * 32 + n * 16 + li) * 64 + (((c * 4 + hi) ^ (li & 7)) << 3)];

    if (z == 2) {
#pragma unroll
      for (int m = 0; m < 4; ++m)
#pragma unroll
        for (int n = 0; n < 2; ++n)
#pragma unroll
          for (int c = 0; c < 2; ++c)
            acc[m][n] = __builtin_amdgcn_mfma_f32_16x16x32_bf16(a[m][c], b[n][c], acc[m][n], 0, 0, 0);
    } else {  // swapped: acc = C^T fragment (row=feature, col=token)
#pragma unroll
      for (int m = 0; m < 4; ++m)
#pragma unroll
        for (int n = 0; n < 2; ++n)
#pragma unroll
          for (int c = 0; c < 2; ++c)
            acc[m][n] = __builtin_amdgcn_mfma_f32_16x16x32_bf16(b[n][c], a[m][c], acc[m][n], 0, 0, 0);
    }
  }

#pragma unroll
  for (int m = 0; m < 4; ++m)
#pragma unroll
    for (int n = 0; n < 2; ++n) {
      if (z == 2) {
        int token0 = row0 + wm * 64 + m * 16 + hi * 4;
        int col    = col0 + wn * 32 + n * 16 + li;
        int b_ = token0 >> 11, t0 = token0 & (NT - 1);
        int h_ = col >> 6,     d_ = col & (NHD - 1);
        uint2 w;
        w.x = pk2bf(acc[m][n][0], acc[m][n][1]);
        w.y = pk2bf(acc[m][n][2], acc[m][n][3]);
        *(uint2*)&osel[(((size_t)(b_ * NH + h_)) * NHD + d_) * NT + t0] = w;
      } else {
        int token = row0 + wm * 64 + m * 16 + li;
        int feat0 = col0 + wn * 32 + n * 16 + hi * 4;
        int b_ = token >> 11, t_ = token & (NT - 1);
        int h_ = feat0 >> 6,  d0 = feat0 & (NHD - 1);
        uint2 w;
        w.x = pk2bf(acc[m][n][0] * scl, acc[m][n][1] * scl);
        w.y = pk2bf(acc[m][n][2] * scl, acc[m][n][3] * scl);
        *(uint2*)&osel[(((size_t)(b_ * NH + h_)) * NT + t_) * NHD + d0] = w;
      }
    }
}

// ---------------- WO GEMM + residual, same distance-2 pipeline (r14) ----------------
__global__ __launch_bounds__(512, 2) void gemm_wo3(
    const u16* __restrict__ ao, const u16* __restrict__ wob,
    const float* __restrict__ x, float* __restrict__ y) {
  const int row0 = blockIdx.x << 7;
  const int col0 = blockIdx.y << 7;

  const int tid  = threadIdx.x;
  const int lane = tid & 63, wid = tid >> 6;
  const int wm = wid >> 2, wn = wid & 3;
  const int li = lane & 15, hi = lane >> 4;
  const int l3 = lane >> 3, sl = lane & 7;
  const int schunk = ((sl ^ l3) << 3);

  extern __shared__ __align__(16) u16 smem[];
  u16* lAb = smem;
  u16* lBb = smem + 3 * 128 * 64;

  auto stage = [&](int t) {
    const int bo = (t % 3) * 8192;
    const int k0 = t << 6;
#pragma unroll
    for (int h = 0; h < 2; ++h) {
      int r = h * 64 + wid * 8;
      gll16(&ao [(size_t)(row0 + r + l3) * ND + k0 + schunk], &lAb[bo + r * 64]);
      gll16(&wob[(size_t)(col0 + r + l3) * ND + k0 + schunk], &lBb[bo + r * 64]);
    }
  };

  f32x4 acc[4][2] = {};

  stage(0);
  stage(1);

  for (int i = 0; i < 16; ++i) {
    if (i < 15) { asm volatile("s_waitcnt vmcnt(4)" ::: "memory"); }
    else        { asm volatile("s_waitcnt vmcnt(0)" ::: "memory"); }
    __builtin_amdgcn_s_barrier();

    if (i + 2 < 16) stage(i + 2);

    const u16* la = &lAb[(i % 3) * 8192];
    const u16* lb = &lBb[(i % 3) * 8192];

    short8 a[4][2], b[2][2];
#pragma unroll
    for (int m = 0; m < 4; ++m)
#pragma unroll
      for (int c = 0; c < 2; ++c)
        a[m][c] = *(const short8*)&la[(wm * 64 + m * 16 + li) * 64 + (((c * 4 + hi) ^ (li & 7)) << 3)];
#pragma unroll
    for (int n = 0; n < 2; ++n)
#pragma unroll
      for (int c = 0; c < 2; ++c)
        b[n][c] = *(const short8*)&lb[(wn * 32 + n * 16 + li) * 64 + (((c * 4 + hi) ^ (li & 7)) << 3)];

#pragma unroll
    for (int m = 0; m < 4; ++m)
#pragma unroll
      for (int n = 0; n < 2; ++n)
#pragma unroll
        for (int c = 0; c < 2; ++c)
          acc[m][n] = __builtin_amdgcn_mfma_f32_16x16x32_bf16(b[n][c], a[m][c], acc[m][n], 0, 0, 0);
  }

#pragma unroll
  for (int m = 0; m < 4; ++m)
#pragma unroll
    for (int n = 0; n < 2; ++n) {
      int token = row0 + wm * 64 + m * 16 + li;
      int feat0 = col0 + wn * 32 + n * 16 + hi * 4;
      size_t idx = (size_t)token * ND + feat0;
      float4 xv = *(const float4*)&x[idx];
      float4 o;
      o.x = acc[m][n][0] + xv.x; o.y = acc[m][n][1] + xv.y;
      o.z = acc[m][n][2] + xv.z; o.w = acc[m][n][3] + xv.w;
      *(float4*)&y[idx] = o;
    }
}

// ---------------- causal flash attention: 128 q-rows/block, deferred-PV ----------------
// r16 structure with DOUBLED q-tile: 8 waves x 16 q-rows share each K/V tile, so K/V
// staging bytes, issue/commit instructions, and barrier-iterations are all HALVED per
// useful wave-tile (33792 -> 17408 instances; useful work identical: 135168 wave-tiles).
// LDS 56KB static -> 2 blocks/CU x 512thr = 16 waves/CU (was 12). Heavy-first kept.
// Wave-uniform `act` skips fully-masked tiles; deferred PV guarded by prevAct.
__global__ __launch_bounds__(512) void attn_kernel(
    const u16* __restrict__ Q, const u16* __restrict__ K, const u16* __restrict__ VT,
    u16* __restrict__ AO) {
  // T1: XCD-aware swizzle (1024 % 8 == 0 -> bijective)
  const int nb  = gridDim.x * gridDim.y;           // 1024
  const int b0  = blockIdx.y * gridDim.x + blockIdx.x;
  const int L   = (b0 & 7) * (nb >> 3) + (b0 >> 3);
  const int qs  = 15 - (L & 15);     // heavy-first: big q-supertile dispatched early
  const int bh  = L >> 4;            // 0..63

  const int tid = threadIdx.x;
  const int lane = tid & 63, wid = tid >> 6;   // 8 waves
  const int li = lane & 15, hi = lane >> 4;
  const int r0 = qs * 128 + wid * 16;          // wave's q rows
  const int qrow = r0 + li;
  const size_t bK = (size_t)bh * NT * NHD;     // K  [bh][t][d]
  const size_t bV = (size_t)bh * NHD * NT;     // VT [bh][d][t]

  __shared__ __align__(16) u16 lK [2][64 * 64];   // 16 KB
  __shared__ __align__(16) u16 lVT[3][64 * 64];   // 24 KB
  __shared__ __align__(16) u16 lP [8][16 * 64];   // 16 KB

  // staging: 512 chunks of 8 u16 per 64x64 tile; thread owns chunk ch = tid
  const int ch = tid;
  const int dd   = (ch >> 3) * 64 + (((ch & 7) ^ ((ch >> 3) & 7)) << 3);
  const int vOff = (ch >> 3) * NT + (ch & 7) * 8;

  uint4 gK0, gV0;
  auto issue = [&](int kt) {
    gK0 = *(const uint4*)&K [bK + (size_t)kt * 4096 + ch * 8];
    gV0 = *(const uint4*)&VT[bV + (size_t)kt * 64 + vOff];
  };
  auto commit = [&](int kt) {          // K double-buffer (kt&1), V triple-buffer (kt%3)
    *(uint4*)&lK [kt & 1][dd] = gK0;
    *(uint4*)&lVT[kt % 3][dd] = gV0;
  };

  // Q fragments (B-operand): lane holds Q[qrow][c*32 + hi*8 + e]
  short8 qf[2];
#pragma unroll
  for (int c = 0; c < 2; ++c)
    qf[c] = *(const short8*)&Q[bK + (size_t)qrow * NHD + c * 32 + hi * 8];

  short8 vone;
#pragma unroll
  for (int e = 0; e < 8; ++e) vone[e] = (short)0x3F80;   // bf16 1.0

  f32x4 o[4] = {};
  f32x4 o4 = {};             // rowsum accumulator (all 4 regs equal)
  short8 pap0 = {}, pap1 = {};
  bool prevAct = false;

  issue(0);
  commit(0);
  __syncthreads();

  const int nkt = 2 * qs + 2;
  const int pswz = (li & 7) << 1;   // P-LDS XOR swizzle (8B chunks, bit0 preserved)

  for (int kt = 0; kt < nkt; ++kt) {
    if (kt + 1 < nkt) issue(kt + 1);      // global loads in flight under compute

    const bool act = (kt * 64 <= r0 + 15);  // wave-uniform: some row of this wave unmasked

    // S^T = K Q^T from lK[kt&1]
    f32x4 s[4] = {};
    __builtin_amdgcn_s_setprio(1);
    if (act) {
#pragma unroll
      for (int g = 0; g < 4; ++g)
#pragma unroll
        for (int c = 0; c < 2; ++c) {
          short8 kf = *(const short8*)&lK[kt & 1][(g * 16 + li) * 64 + ((c * 4 + hi) ^ (li & 7)) * 8];
          s[g] = __builtin_amdgcn_mfma_f32_16x16x32_bf16(kf, qf[c], s[g], 0, 0, 0);
        }
    }

    // deferred PV(kt-1): independent of s -> fills QK's LDS-read shadow
    if (prevAct) {
      const u16* lv = lVT[(kt - 1) % 3];
#pragma unroll
      for (int gd = 0; gd < 4; ++gd) {
        short8 vf0 = *(const short8*)&lv[(gd * 16 + li) * 64 + ((0 * 4 + hi) ^ (li & 7)) * 8];
        short8 vf1 = *(const short8*)&lv[(gd * 16 + li) * 64 + ((1 * 4 + hi) ^ (li & 7)) * 8];
        o[gd] = __builtin_amdgcn_mfma_f32_16x16x32_bf16(vf0, pap0, o[gd], 0, 0, 0);
        o[gd] = __builtin_amdgcn_mfma_f32_16x16x32_bf16(vf1, pap1, o[gd], 0, 0, 0);
      }
      o4 = __builtin_amdgcn_mfma_f32_16x16x32_bf16(vone, pap0, o4, 0, 0, 0);
      o4 = __builtin_amdgcn_mfma_f32_16x16x32_bf16(vone, pap1, o4, 0, 0, 0);
    }
    __builtin_amdgcn_s_setprio(0);

    if (act) {
      if (kt >= nkt - 2) {                 // causal mask near the diagonal
#pragma unroll
        for (int g = 0; g < 4; ++g)
#pragma unroll
          for (int rg = 0; rg < 4; ++rg) {
            int kcol = kt * 64 + g * 16 + hi * 4 + rg;
            if (kcol > qrow) s[g][rg] = -INFINITY;
          }
      }

      // P = exp2(S) -> LDS as bf16 (static-max; exp2(-inf)=0 handles the mask)
#pragma unroll
      for (int g = 0; g < 4; ++g) {
        float p0 = __builtin_amdgcn_exp2f(s[g][0]);
        float p1 = __builtin_amdgcn_exp2f(s[g][1]);
        float p2 = __builtin_amdgcn_exp2f(s[g][2]);
        float p3 = __builtin_amdgcn_exp2f(s[g][3]);
        uint2 w;
        w.x = pk2bf(p0, p1);
        w.y = pk2bf(p2, p3);
        int k8s = (g * 4 + hi) ^ pswz;
        *(uint2*)&lP[wid][li * 64 + k8s * 4] = w;
      }

      // read pa(kt) (per-wave-private lP: lgkm-only dependency, drains under barrier)
      pap0 = *(const short8*)&lP[wid][li * 64 + ((0 * 8 + hi * 2) ^ pswz) * 4];
      pap1 = *(const short8*)&lP[wid][li * 64 + ((1 * 8 + hi * 2) ^ pswz) * 4];
    }
    prevAct = act;

    if (kt + 1 < nkt) commit(kt + 1);   // vmcnt consumed here (hidden under compute)
    __syncthreads();
  }

  // final PV for the last active tile (waves 4-7; waves 0-3 finished inside loop)
  if (prevAct) {
    const u16* lv = lVT[(nkt - 1) % 3];
#pragma unroll
    for (int gd = 0; gd < 4; ++gd) {
      short8 vf0 = *(const short8*)&lv[(gd * 16 + li) * 64 + ((0 * 4 + hi) ^ (li & 7)) * 8];
      short8 vf1 = *(const short8*)&lv[(gd * 16 + li) * 64 + ((1 * 4 + hi) ^ (li & 7)) * 8];
      o[gd] = __builtin_amdgcn_mfma_f32_16x16x32_bf16(vf0, pap0, o[gd], 0, 0, 0);
      o[gd] = __builtin_amdgcn_mfma_f32_16x16x32_bf16(vf1, pap1, o[gd], 0, 0, 0);
    }
    o4 = __builtin_amdgcn_mfma_f32_16x16x32_bf16(vone, pap0, o4, 0, 0, 0);
    o4 = __builtin_amdgcn_mfma_f32_16x16x32_bf16(vone, pap1, o4, 0, 0, 0);
  }

  // epilogue: O /= rowsum; pack 4 bf16 (8B) per gd and store
  const int b_ = bh >> 4, h_ = bh & 15;
  const float inv = 1.0f / o4[0];
  const size_t rowbase = ((size_t)(b_ * NT + qrow)) * ND + h_ * 64;
#pragma unroll
  for (int gd = 0; gd < 4; ++gd) {
    uint2 w;
    w.x = pk2bf(o[gd][0] * inv, o[gd][1] * inv);
    w.y = pk2bf(o[gd][2] * inv, o[gd][3] * inv);
    *(uint2*)&AO[rowbase + gd * 16 + hi * 4] = w;
  }
}

// ---------------- RMSNorm in-place on d_out ----------------
__global__ __launch_bounds__(256) void rmsnorm_kernel(float* __restrict__ y,
                                                      const float* __restrict__ g) {
  const int row = blockIdx.x;
  const int tid = threadIdx.x;
  const int lane = tid & 63, wid = tid >> 6;
  float4 v = ((const float4*)(y + (size_t)row * ND))[tid];
  float ss = v.x * v.x + v.y * v.y + v.z * v.z + v.w * v.w;
#pragma unroll
  for (int off = 32; off; off >>= 1) ss += __shfl_down(ss, off);
  __shared__ float red[4];
  if (lane == 0) red[wid] = ss;
  __syncthreads();
  float tot = red[0] + red[1] + red[2] + red[3];
  float inv = rsqrtf(tot * (1.0f / (float)ND) + 1e-6f);
  float4 gg = ((const float4*)g)[tid];
  float4 o;
  o.x = v.x * inv * gg.x; o.y = v.y * inv * gg.y;
  o.z = v.z * inv * gg.z; o.w = v.w * inv * gg.w;
  ((float4*)(y + (size_t)row * ND))[tid] = o;
}

extern "C" void kernel_launch(void* const* d_in, const int* in_sizes, int n_in,
                              void* d_out, int out_size, void* d_ws, size_t ws_size,
                              hipStream_t stream) {
  const float* x  = (const float*)d_in[0];
  const float* wq = (const float*)d_in[1];
  const float* wk = (const float*)d_in[2];
  const float* wv = (const float*)d_in[3];
  const float* wo = (const float*)d_in[4];
  const float* ng = (const float*)d_in[5];
  float* out = (float*)d_out;

  char* ws = (char*)d_ws;
  u16* xb  = (u16*)(ws);                    // 16 MB  [M, D] bf16
  u16* wqb = (u16*)(ws + (16u << 20));      //  2 MB
  u16* wkb = (u16*)(ws + (18u << 20));
  u16* wvb = (u16*)(ws + (20u << 20));
  u16* wob = (u16*)(ws + (22u << 20));
  u16* Qb  = (u16*)(ws + (24u << 20));      // 16 MB  [B,H,T,HD]
  u16* Kb  = (u16*)(ws + (40u << 20));      // 16 MB  [B,H,T,HD]
  u16* VTb = (u16*)(ws + (56u << 20));      // 16 MB  [B,H,HD,T]  (transposed V)
  u16* AO  = (u16*)(ws + (72u << 20));      // 16 MB  [M, D]  (ends at 88 MB)

  cast_all<<<8192 + 4096, 256, 0, stream>>>(x, wq, wk, wv, wo, xb, wqb, wkb, wvb, wob);

  gemm_qkv3<<<dim3(64, 8, 3), 512, 98304, stream>>>(xb, wqb, wkb, wvb, Qb, Kb, VTb);
  attn_kernel<<<dim3(16, NB * NH), 512, 0, stream>>>(Qb, Kb, VTb, AO);
  gemm_wo3<<<dim3(64, 8), 512, 98304, stream>>>(AO, wob, x, out);
  rmsnorm_kernel<<<NM, 256, 0, stream>>>(out, ng);
}

// Round 18
// 200.118 us; speedup vs baseline: 1.0285x; 1.0285x over previous
//
#include <hip/hip_runtime.h>
#include <hip/hip_bf16.h>

// Problem constants (B=4, T=2048, D=1024, H=16, HD=64)
constexpr int NB  = 4;
constexpr int NT  = 2048;
constexpr int ND  = 1024;
constexpr int NH  = 16;
constexpr int NHD = 64;
constexpr int NM  = NB * NT;   // 8192 tokens

typedef unsigned short u16;
typedef __attribute__((ext_vector_type(8))) short  short8;  // 8 bf16 (4 VGPRs)
typedef __attribute__((ext_vector_type(4))) float  f32x4;   // MFMA acc

__device__ __forceinline__ u16 f2bf(float f) {
  unsigned u = __builtin_bit_cast(unsigned, f);
  u += 0x7FFFu + ((u >> 16) & 1u);   // round-to-nearest-even
  return (u16)(u >> 16);
}

// pack two f32 -> 2x bf16 in one dword (compiler emits v_cvt_pk_bf16_f32)
__device__ __forceinline__ unsigned pk2bf(float lo, float hi_) {
  float2 t; t.x = lo; t.y = hi_;
  __hip_bfloat162 h2 = __float22bfloat162_rn(t);
  unsigned u;
  __builtin_memcpy(&u, &h2, 4);
  return u;
}

// async global->LDS, 16B per lane. dst must be wave-uniform; lane i lands at dst + i*16B.
__device__ __forceinline__ void gll16(const u16* src, u16* dst) {
  __builtin_amdgcn_global_load_lds(
      (const __attribute__((address_space(1))) void*)src,
      (__attribute__((address_space(3))) void*)dst, 16, 0, 0);
}

// ---------------- fused cast: x (8192 blocks) + 4 weights (1024 blocks each) ----------------
__global__ __launch_bounds__(256) void cast_all(
    const float* __restrict__ x,
    const float* __restrict__ w0, const float* __restrict__ w1,
    const float* __restrict__ w2, const float* __restrict__ w3,
    u16* __restrict__ xb,
    u16* __restrict__ o0, u16* __restrict__ o1,
    u16* __restrict__ o2, u16* __restrict__ o3) {
  const int bid = blockIdx.x;
  const float* in;
  u16* out;
  int i;
  if (bid < 8192) {
    in = x; out = xb; i = bid * 256 + threadIdx.x;
  } else {
    const int z = (bid - 8192) >> 10;
    in  = (z == 0) ? w0 : (z == 1) ? w1 : (z == 2) ? w2 : w3;
    out = (z == 0) ? o0 : (z == 1) ? o1 : (z == 2) ? o2 : o3;
    i = ((bid - 8192) & 1023) * 256 + threadIdx.x;
  }
  float4 v = ((const float4*)in)[i];
  ushort4 o;
  o.x = f2bf(v.x); o.y = f2bf(v.y); o.z = f2bf(v.z); o.w = f2bf(v.w);
  ((ushort4*)out)[i] = o;
}

// ---------------- QKV GEMM: distance-2 triple-buffer pipeline (r14, 82.5us verified) ----------
__global__ __launch_bounds__(512, 2) void gemm_qkv3(
    const u16* __restrict__ xb,
    const u16* __restrict__ wqb, const u16* __restrict__ wkb, const u16* __restrict__ wvb,
    u16* __restrict__ Qb, u16* __restrict__ Kb, u16* __restrict__ VTb) {
  const int z    = blockIdx.z;
  const int row0 = blockIdx.x << 7;
  const int col0 = blockIdx.y << 7;

  const u16* wsel = (z == 0) ? wqb : (z == 1) ? wkb : wvb;
  u16* osel      = (z == 0) ? Qb  : (z == 1) ? Kb  : VTb;
  const float scl = (z == 0) ? 0.125f * 1.44269504f : 1.0f;  // scale+log2e into Q

  const int tid  = threadIdx.x;
  const int lane = tid & 63, wid = tid >> 6;   // 8 waves
  const int wm = wid >> 2, wn = wid & 3;       // 2 x 4 wave grid
  const int li = lane & 15, hi = lane >> 4;
  const int l3 = lane >> 3, sl = lane & 7;
  const int schunk = ((sl ^ l3) << 3);         // pre-swizzled source chunk (row&7 == l3)

  extern __shared__ __align__(16) u16 smem[];  // 96 KB: 3 x (A 16KB + B 16KB)
  u16* lAb = smem;                              // [3][128*64]
  u16* lBb = smem + 3 * 128 * 64;               // [3][128*64]

  auto stage = [&](int t) {
    const int bo = (t % 3) * 8192;
    const int k0 = t << 6;
#pragma unroll
    for (int h = 0; h < 2; ++h) {
      int r = h * 64 + wid * 8;
      gll16(&xb  [(size_t)(row0 + r + l3) * ND + k0 + schunk], &lAb[bo + r * 64]);
      gll16(&wsel[(size_t)(col0 + r + l3) * ND + k0 + schunk], &lBb[bo + r * 64]);
    }
  };

  f32x4 acc[4][2] = {};

  stage(0);
  stage(1);

  for (int i = 0; i < 16; ++i) {
    if (i < 15) { asm volatile("s_waitcnt vmcnt(4)" ::: "memory"); }
    else        { asm volatile("s_waitcnt vmcnt(0)" ::: "memory"); }
    __builtin_amdgcn_s_barrier();

    if (i + 2 < 16) stage(i + 2);

    const u16* la = &lAb[(i % 3) * 8192];
    const u16* lb = &lBb[(i % 3) * 8192];

    short8 a[4][2], b[2][2];
#pragma unroll
    for (int m = 0; m < 4; ++m)
#pragma unroll
      for (int c = 0; c < 2; ++c)
        a[m][c] = *(const short8*)&la[(wm * 64 + m * 16 + li) * 64 + (((c * 4 + hi) ^ (li & 7)) << 3)];
#pragma unroll
    for (int n = 0; n < 2; ++n)
#pragma unroll
      for (int c = 0; c < 2; ++c)
        b[n][c] = *(const short8*)&lb[(wn * 32 + n * 16 + li) * 64 + (((c * 4 + hi) ^ (li & 7)) << 3)];

    if (z == 2) {
#pragma unroll
      for (int m = 0; m < 4; ++m)
#pragma unroll
        for (int n = 0; n < 2; ++n)
#pragma unroll
          for (int c = 0; c < 2; ++c)
            acc[m][n] = __builtin_amdgcn_mfma_f32_16x16x32_bf16(a[m][c], b[n][c], acc[m][n], 0, 0, 0);
    } else {  // swapped: acc = C^T fragment (row=feature, col=token)
#pragma unroll
      for (int m = 0; m < 4; ++m)
#pragma unroll
        for (int n = 0; n < 2; ++n)
#pragma unroll
          for (int c = 0; c < 2; ++c)
            acc[m][n] = __builtin_amdgcn_mfma_f32_16x16x32_bf16(b[n][c], a[m][c], acc[m][n], 0, 0, 0);
    }
  }

#pragma unroll
  for (int m = 0; m < 4; ++m)
#pragma unroll
    for (int n = 0; n < 2; ++n) {
      if (z == 2) {
        int token0 = row0 + wm * 64 + m * 16 + hi * 4;
        int col    = col0 + wn * 32 + n * 16 + li;
        int b_ = token0 >> 11, t0 = token0 & (NT - 1);
        int h_ = col >> 6,     d_ = col & (NHD - 1);
        uint2 w;
        w.x = pk2bf(acc[m][n][0], acc[m][n][1]);
        w.y = pk2bf(acc[m][n][2], acc[m][n][3]);
        *(uint2*)&osel[(((size_t)(b_ * NH + h_)) * NHD + d_) * NT + t0] = w;
      } else {
        int token = row0 + wm * 64 + m * 16 + li;
        int feat0 = col0 + wn * 32 + n * 16 + hi * 4;
        int b_ = token >> 11, t_ = token & (NT - 1);
        int h_ = feat0 >> 6,  d0 = feat0 & (NHD - 1);
        uint2 w;
        w.x = pk2bf(acc[m][n][0] * scl, acc[m][n][1] * scl);
        w.y = pk2bf(acc[m][n][2] * scl, acc[m][n][3] * scl);
        *(uint2*)&osel[(((size_t)(b_ * NH + h_)) * NT + t_) * NHD + d0] = w;
      }
    }
}

// ---------------- WO GEMM + residual, same distance-2 pipeline (r14) ----------------
__global__ __launch_bounds__(512, 2) void gemm_wo3(
    const u16* __restrict__ ao, const u16* __restrict__ wob,
    const float* __restrict__ x, float* __restrict__ y) {
  const int row0 = blockIdx.x << 7;
  const int col0 = blockIdx.y << 7;

  const int tid  = threadIdx.x;
  const int lane = tid & 63, wid = tid >> 6;
  const int wm = wid >> 2, wn = wid & 3;
  const int li = lane & 15, hi = lane >> 4;
  const int l3 = lane >> 3, sl = lane & 7;
  const int schunk = ((sl ^ l3) << 3);

  extern __shared__ __align__(16) u16 smem[];
  u16* lAb = smem;
  u16* lBb = smem + 3 * 128 * 64;

  auto stage = [&](int t) {
    const int bo = (t % 3) * 8192;
    const int k0 = t << 6;
#pragma unroll
    for (int h = 0; h < 2; ++h) {
      int r = h * 64 + wid * 8;
      gll16(&ao [(size_t)(row0 + r + l3) * ND + k0 + schunk], &lAb[bo + r * 64]);
      gll16(&wob[(size_t)(col0 + r + l3) * ND + k0 + schunk], &lBb[bo + r * 64]);
    }
  };

  f32x4 acc[4][2] = {};

  stage(0);
  stage(1);

  for (int i = 0; i < 16; ++i) {
    if (i < 15) { asm volatile("s_waitcnt vmcnt(4)" ::: "memory"); }
    else        { asm volatile("s_waitcnt vmcnt(0)" ::: "memory"); }
    __builtin_amdgcn_s_barrier();

    if (i + 2 < 16) stage(i + 2);

    const u16* la = &lAb[(i % 3) * 8192];
    const u16* lb = &lBb[(i % 3) * 8192];

    short8 a[4][2], b[2][2];
#pragma unroll
    for (int m = 0; m < 4; ++m)
#pragma unroll
      for (int c = 0; c < 2; ++c)
        a[m][c] = *(const short8*)&la[(wm * 64 + m * 16 + li) * 64 + (((c * 4 + hi) ^ (li & 7)) << 3)];
#pragma unroll
    for (int n = 0; n < 2; ++n)
#pragma unroll
      for (int c = 0; c < 2; ++c)
        b[n][c] = *(const short8*)&lb[(wn * 32 + n * 16 + li) * 64 + (((c * 4 + hi) ^ (li & 7)) << 3)];

#pragma unroll
    for (int m = 0; m < 4; ++m)
#pragma unroll
      for (int n = 0; n < 2; ++n)
#pragma unroll
        for (int c = 0; c < 2; ++c)
          acc[m][n] = __builtin_amdgcn_mfma_f32_16x16x32_bf16(b[n][c], a[m][c], acc[m][n], 0, 0, 0);
  }

#pragma unroll
  for (int m = 0; m < 4; ++m)
#pragma unroll
    for (int n = 0; n < 2; ++n) {
      int token = row0 + wm * 64 + m * 16 + li;
      int feat0 = col0 + wn * 32 + n * 16 + hi * 4;
      size_t idx = (size_t)token * ND + feat0;
      float4 xv = *(const float4*)&x[idx];
      float4 o;
      o.x = acc[m][n][0] + xv.x; o.y = acc[m][n][1] + xv.y;
      o.z = acc[m][n][2] + xv.z; o.w = acc[m][n][3] + xv.w;
      *(float4*)&y[idx] = o;
    }
}

// ---------------- causal flash attention: deferred-PV pipeline (r16, 200.4us verified) -------
// 64 q-rows/block (uniform per-block work -- r5/r17 both showed wider causal tiles lose
// to barrier-locked idle waves). Deferred PV(kt-1) on register-held pa overlaps QK(kt)'s
// LDS-read shadow; V triple-buffered; static-max softmax with ones-MFMA rowsum.
__global__ __launch_bounds__(256) void attn_kernel(
    const u16* __restrict__ Q, const u16* __restrict__ K, const u16* __restrict__ VT,
    u16* __restrict__ AO) {
  // T1: XCD-aware swizzle (2048 % 8 == 0 -> bijective)
  const int nb  = gridDim.x * gridDim.y;           // 2048
  const int b0  = blockIdx.y * gridDim.x + blockIdx.x;
  const int L   = (b0 & 7) * (nb >> 3) + (b0 >> 3);
  const int qb  = 31 - (L & 31);     // heavy-first: big qb dispatched early
  const int bh  = L >> 5;            // 0..63

  const int tid = threadIdx.x;
  const int lane = tid & 63, wid = tid >> 6;
  const int li = lane & 15, hi = lane >> 4;
  const int r0 = qb * 64 + wid * 16;         // wave's q rows
  const int qrow = r0 + li;                  // this lane's q row
  const size_t bK = (size_t)bh * NT * NHD;   // K  [bh][t][d]
  const size_t bV = (size_t)bh * NHD * NT;   // VT [bh][d][t]

  __shared__ __align__(16) u16 lK [2][64 * 64];
  __shared__ __align__(16) u16 lVT[3][64 * 64];
  __shared__ __align__(16) u16 lP [4][16 * 64];

  // reg-staging geometry: 512 chunks of 8 u16 per tile; thread owns ch0=tid, ch1=tid+256
  const int ch0 = tid, ch1 = tid + 256;
  const int d0 = (ch0 >> 3) * 64 + (((ch0 & 7) ^ ((ch0 >> 3) & 7)) << 3);
  const int d1 = (ch1 >> 3) * 64 + (((ch1 & 7) ^ ((ch1 >> 3) & 7)) << 3);
  const int vOff0 = (ch0 >> 3) * NT + (ch0 & 7) * 8;
  const int vOff1 = (ch1 >> 3) * NT + (ch1 & 7) * 8;

  uint4 gK0, gK1, gV0, gV1;
  auto issue = [&](int kt) {
    const u16* kp = K + bK + (size_t)kt * 4096;
    const u16* vp = VT + bV + kt * 64;
    gK0 = *(const uint4*)&kp[ch0 * 8];
    gK1 = *(const uint4*)&kp[ch1 * 8];
    gV0 = *(const uint4*)&vp[vOff0];
    gV1 = *(const uint4*)&vp[vOff1];
  };
  auto commit = [&](int kt) {          // K double-buffer (kt&1), V triple-buffer (kt%3)
    *(uint4*)&lK [kt & 1][d0] = gK0;
    *(uint4*)&lK [kt & 1][d1] = gK1;
    *(uint4*)&lVT[kt % 3][d0] = gV0;
    *(uint4*)&lVT[kt % 3][d1] = gV1;
  };

  // Q fragments (B-operand): lane holds Q[qrow][c*32 + hi*8 + e]
  short8 qf[2];
#pragma unroll
  for (int c = 0; c < 2; ++c)
    qf[c] = *(const short8*)&Q[bK + (size_t)qrow * NHD + c * 32 + hi * 8];

  short8 vone;
#pragma unroll
  for (int e = 0; e < 8; ++e) vone[e] = (short)0x3F80;   // bf16 1.0

  f32x4 o[4] = {};
  f32x4 o4 = {};             // rowsum accumulator (all 4 regs equal)
  short8 pap0, pap1;         // pa of previous tile (named scalars - no dyn indexing)

  issue(0);
  commit(0);
  __syncthreads();

  const int pswz = (li & 7) << 1;   // P-LDS XOR swizzle (8B chunks, bit0 preserved)

  for (int kt = 0; kt <= qb; ++kt) {
    if (kt < qb) issue(kt + 1);    // global loads in flight under the compute below

    // S^T = K Q^T from lK[kt&1]
    f32x4 s[4] = {};
    __builtin_amdgcn_s_setprio(1);
#pragma unroll
    for (int g = 0; g < 4; ++g)
#pragma unroll
      for (int c = 0; c < 2; ++c) {
        short8 kf = *(const short8*)&lK[kt & 1][(g * 16 + li) * 64 + ((c * 4 + hi) ^ (li & 7)) * 8];
        s[g] = __builtin_amdgcn_mfma_f32_16x16x32_bf16(kf, qf[c], s[g], 0, 0, 0);
      }

    // deferred PV(kt-1): independent of s -> fills QK's LDS-read shadow
    if (kt > 0) {
      const u16* lv = lVT[(kt - 1) % 3];
#pragma unroll
      for (int gd = 0; gd < 4; ++gd) {
        short8 vf0 = *(const short8*)&lv[(gd * 16 + li) * 64 + ((0 * 4 + hi) ^ (li & 7)) * 8];
        short8 vf1 = *(const short8*)&lv[(gd * 16 + li) * 64 + ((1 * 4 + hi) ^ (li & 7)) * 8];
        o[gd] = __builtin_amdgcn_mfma_f32_16x16x32_bf16(vf0, pap0, o[gd], 0, 0, 0);
        o[gd] = __builtin_amdgcn_mfma_f32_16x16x32_bf16(vf1, pap1, o[gd], 0, 0, 0);
      }
      o4 = __builtin_amdgcn_mfma_f32_16x16x32_bf16(vone, pap0, o4, 0, 0, 0);
      o4 = __builtin_amdgcn_mfma_f32_16x16x32_bf16(vone, pap1, o4, 0, 0, 0);
    }
    __builtin_amdgcn_s_setprio(0);

    if (kt == qb) {                          // causal mask on diagonal tile
#pragma unroll
      for (int g = 0; g < 4; ++g)
#pragma unroll
        for (int rg = 0; rg < 4; ++rg) {
          int kcol = kt * 64 + g * 16 + hi * 4 + rg;
          if (kcol > qrow) s[g][rg] = -INFINITY;
        }
    }

    // P = exp2(S) -> LDS as bf16 (static-max; exp2(-inf)=0 handles the mask)
#pragma unroll
    for (int g = 0; g < 4; ++g) {
      float p0 = __builtin_amdgcn_exp2f(s[g][0]);
      float p1 = __builtin_amdgcn_exp2f(s[g][1]);
      float p2 = __builtin_amdgcn_exp2f(s[g][2]);
      float p3 = __builtin_amdgcn_exp2f(s[g][3]);
      uint2 w;
      w.x = pk2bf(p0, p1);
      w.y = pk2bf(p2, p3);
      int k8s = (g * 4 + hi) ^ pswz;
      *(uint2*)&lP[wid][li * 64 + k8s * 4] = w;
    }

    // read pa(kt) (per-wave-private lP: lgkm-only dependency, drains under barrier)
    pap0 = *(const short8*)&lP[wid][li * 64 + ((0 * 8 + hi * 2) ^ pswz) * 4];
    pap1 = *(const short8*)&lP[wid][li * 64 + ((1 * 8 + hi * 2) ^ pswz) * 4];

    if (kt < qb) commit(kt + 1);   // vmcnt consumed here (hidden under compute above)
    __syncthreads();
  }

  // final PV(qb)
  {
    const u16* lv = lVT[qb % 3];
#pragma unroll
    for (int gd = 0; gd < 4; ++gd) {
      short8 vf0 = *(const short8*)&lv[(gd * 16 + li) * 64 + ((0 * 4 + hi) ^ (li & 7)) * 8];
      short8 vf1 = *(const short8*)&lv[(gd * 16 + li) * 64 + ((1 * 4 + hi) ^ (li & 7)) * 8];
      o[gd] = __builtin_amdgcn_mfma_f32_16x16x32_bf16(vf0, pap0, o[gd], 0, 0, 0);
      o[gd] = __builtin_amdgcn_mfma_f32_16x16x32_bf16(vf1, pap1, o[gd], 0, 0, 0);
    }
    o4 = __builtin_amdgcn_mfma_f32_16x16x32_bf16(vone, pap0, o4, 0, 0, 0);
    o4 = __builtin_amdgcn_mfma_f32_16x16x32_bf16(vone, pap1, o4, 0, 0, 0);
  }

  // epilogue: O /= rowsum; pack 4 bf16 (8B) per gd and store
  const int b_ = bh >> 4, h_ = bh & 15;
  const float inv = 1.0f / o4[0];
  const size_t rowbase = ((size_t)(b_ * NT + qrow)) * ND + h_ * 64;
#pragma unroll
  for (int gd = 0; gd < 4; ++gd) {
    uint2 w;
    w.x = pk2bf(o[gd][0] * inv, o[gd][1] * inv);
    w.y = pk2bf(o[gd][2] * inv, o[gd][3] * inv);
    *(uint2*)&AO[rowbase + gd * 16 + hi * 4] = w;
  }
}

// ---------------- RMSNorm in-place on d_out ----------------
__global__ __launch_bounds__(256) void rmsnorm_kernel(float* __restrict__ y,
                                                      const float* __restrict__ g) {
  const int row = blockIdx.x;
  const int tid = threadIdx.x;
  const int lane = tid & 63, wid = tid >> 6;
  float4 v = ((const float4*)(y + (size_t)row * ND))[tid];
  float ss = v.x * v.x + v.y * v.y + v.z * v.z + v.w * v.w;
#pragma unroll
  for (int off = 32; off; off >>= 1) ss += __shfl_down(ss, off);
  __shared__ float red[4];
  if (lane == 0) red[wid] = ss;
  __syncthreads();
  float tot = red[0] + red[1] + red[2] + red[3];
  float inv = rsqrtf(tot * (1.0f / (float)ND) + 1e-6f);
  float4 gg = ((const float4*)g)[tid];
  float4 o;
  o.x = v.x * inv * gg.x; o.y = v.y * inv * gg.y;
  o.z = v.z * inv * gg.z; o.w = v.w * inv * gg.w;
  ((float4*)(y + (size_t)row * ND))[tid] = o;
}

extern "C" void kernel_launch(void* const* d_in, const int* in_sizes, int n_in,
                              void* d_out, int out_size, void* d_ws, size_t ws_size,
                              hipStream_t stream) {
  const float* x  = (const float*)d_in[0];
  const float* wq = (const float*)d_in[1];
  const float* wk = (const float*)d_in[2];
  const float* wv = (const float*)d_in[3];
  const float* wo = (const float*)d_in[4];
  const float* ng = (const float*)d_in[5];
  float* out = (float*)d_out;

  char* ws = (char*)d_ws;
  u16* xb  = (u16*)(ws);                    // 16 MB  [M, D] bf16
  u16* wqb = (u16*)(ws + (16u << 20));      //  2 MB
  u16* wkb = (u16*)(ws + (18u << 20));
  u16* wvb = (u16*)(ws + (20u << 20));
  u16* wob = (u16*)(ws + (22u << 20));
  u16* Qb  = (u16*)(ws + (24u << 20));      // 16 MB  [B,H,T,HD]
  u16* Kb  = (u16*)(ws + (40u << 20));      // 16 MB  [B,H,T,HD]
  u16* VTb = (u16*)(ws + (56u << 20));      // 16 MB  [B,H,HD,T]  (transposed V)
  u16* AO  = (u16*)(ws + (72u << 20));      // 16 MB  [M, D]  (ends at 88 MB)

  cast_all<<<8192 + 4096, 256, 0, stream>>>(x, wq, wk, wv, wo, xb, wqb, wkb, wvb, wob);

  gemm_qkv3<<<dim3(64, 8, 3), 512, 98304, stream>>>(xb, wqb, wkb, wvb, Qb, Kb, VTb);
  attn_kernel<<<dim3(NT / 64, NB * NH), 256, 0, stream>>>(Qb, Kb, VTb, AO);
  gemm_wo3<<<dim3(64, 8), 512, 98304, stream>>>(AO, wob, x, out);
  rmsnorm_kernel<<<NM, 256, 0, stream>>>(out, ng);
}

// Round 19
// 183.496 us; speedup vs baseline: 1.1217x; 1.0906x over previous
//
#include <hip/hip_runtime.h>
#include <hip/hip_bf16.h>

// Problem constants (B=4, T=2048, D=1024, H=16, HD=64)
constexpr int NB  = 4;
constexpr int NT  = 2048;
constexpr int ND  = 1024;
constexpr int NH  = 16;
constexpr int NHD = 64;
constexpr int NM  = NB * NT;   // 8192 tokens

typedef unsigned short u16;
typedef __attribute__((ext_vector_type(8))) short  short8;  // 8 bf16 (4 VGPRs)
typedef __attribute__((ext_vector_type(4))) float  f32x4;   // MFMA acc

__device__ __forceinline__ u16 f2bf(float f) {
  unsigned u = __builtin_bit_cast(unsigned, f);
  u += 0x7FFFu + ((u >> 16) & 1u);   // round-to-nearest-even
  return (u16)(u >> 16);
}

// pack two f32 -> 2x bf16 in one dword (compiler emits v_cvt_pk_bf16_f32)
__device__ __forceinline__ unsigned pk2bf(float lo, float hi_) {
  float2 t; t.x = lo; t.y = hi_;
  __hip_bfloat162 h2 = __float22bfloat162_rn(t);
  unsigned u;
  __builtin_memcpy(&u, &h2, 4);
  return u;
}

// async global->LDS, 16B per lane. dst must be wave-uniform; lane i lands at dst + i*16B.
__device__ __forceinline__ void gll16(const u16* src, u16* dst) {
  __builtin_amdgcn_global_load_lds(
      (const __attribute__((address_space(1))) void*)src,
      (__attribute__((address_space(3))) void*)dst, 16, 0, 0);
}

// ---------------- fused cast: x (8192 blocks) + 4 weights (1024 blocks each) ----------------
__global__ __launch_bounds__(256) void cast_all(
    const float* __restrict__ x,
    const float* __restrict__ w0, const float* __restrict__ w1,
    const float* __restrict__ w2, const float* __restrict__ w3,
    u16* __restrict__ xb,
    u16* __restrict__ o0, u16* __restrict__ o1,
    u16* __restrict__ o2, u16* __restrict__ o3) {
  const int bid = blockIdx.x;
  const float* in;
  u16* out;
  int i;
  if (bid < 8192) {
    in = x; out = xb; i = bid * 256 + threadIdx.x;
  } else {
    const int z = (bid - 8192) >> 10;
    in  = (z == 0) ? w0 : (z == 1) ? w1 : (z == 2) ? w2 : w3;
    out = (z == 0) ? o0 : (z == 1) ? o1 : (z == 2) ? o2 : o3;
    i = ((bid - 8192) & 1023) * 256 + threadIdx.x;
  }
  float4 v = ((const float4*)in)[i];
  ushort4 o;
  o.x = f2bf(v.x); o.y = f2bf(v.y); o.z = f2bf(v.z); o.w = f2bf(v.w);
  ((ushort4*)out)[i] = o;
}

// ---------------- z-MERGED QKV GEMM ----------------
// One block computes Q, K, V for the same 128-token x 128-feature panel: the x tile is
// staged ONCE per K-step and feeds 3 B tiles -> 48 MFMA per barrier pair (3x the r14
// structure). The 2-phase family is barrier-overhead-bound (~25% MfmaUtil at 16
// MFMA/barrier); tripling MFMA per sync amortizes that bound, and 48 MFMAs (~800cy)
// between gll16 issue and the vmcnt(0) drain cover HBM latency even at distance-1.
// LDS 128KB = 2buf x (A 16KB + 3x B 16KB). Swizzle/fragments identical to r14 (verified).
__global__ __launch_bounds__(512, 2) void gemm_qkvm(
    const u16* __restrict__ xb,
    const u16* __restrict__ wqb, const u16* __restrict__ wkb, const u16* __restrict__ wvb,
    u16* __restrict__ Qb, u16* __restrict__ Kb, u16* __restrict__ VTb) {
  const int row0 = blockIdx.x << 7;
  const int col0 = blockIdx.y << 7;
  const float scl = 0.125f * 1.44269504f;      // attention scale + log2e folded into Q

  const int tid  = threadIdx.x;
  const int lane = tid & 63, wid = tid >> 6;   // 8 waves
  const int wm = wid >> 2, wn = wid & 3;       // 2 x 4 wave grid; wave out 64x32 per matrix
  const int li = lane & 15, hi = lane >> 4;
  const int l3 = lane >> 3, sl = lane & 7;
  const int schunk = ((sl ^ l3) << 3);         // pre-swizzled source chunk (row&7 == l3)

  extern __shared__ __align__(16) u16 smem[];  // 128 KB
  u16* lA = smem;                               // [2][128*64]
  u16* lB = smem + 2 * 128 * 64;                // [2][3][128*64]

  // stage K-tile t into buffer t&1: per wave 2 gll16 for A + 6 for B (8 vmem ops)
  auto stage = [&](int t) {
    const int bf = t & 1;
    const int k0 = t << 6;
#pragma unroll
    for (int h = 0; h < 2; ++h) {
      int r = h * 64 + wid * 8;
      size_t go = (size_t)(col0 + r + l3) * ND + k0 + schunk;
      gll16(&xb [(size_t)(row0 + r + l3) * ND + k0 + schunk], &lA[bf * 8192 + r * 64]);
      gll16(&wqb[go], &lB[(bf * 3 + 0) * 8192 + r * 64]);
      gll16(&wkb[go], &lB[(bf * 3 + 1) * 8192 + r * 64]);
      gll16(&wvb[go], &lB[(bf * 3 + 2) * 8192 + r * 64]);
    }
  };

  f32x4 acc[3][4][2] = {};

  stage(0);
  asm volatile("s_waitcnt vmcnt(0)" ::: "memory");
  __builtin_amdgcn_s_barrier();

  for (int i = 0; i < 16; ++i) {
    if (i + 1 < 16) stage(i + 1);   // issue next tile; lands during the 48 MFMAs below

    const u16* la = &lA[(i & 1) * 8192];

    short8 a[4][2];
#pragma unroll
    for (int m = 0; m < 4; ++m)
#pragma unroll
      for (int c = 0; c < 2; ++c)
        a[m][c] = *(const short8*)&la[(wm * 64 + m * 16 + li) * 64 + (((c * 4 + hi) ^ (li & 7)) << 3)];

#pragma unroll
    for (int z = 0; z < 3; ++z) {
      const u16* lb = &lB[((i & 1) * 3 + z) * 8192];
      short8 b[2][2];
#pragma unroll
      for (int n = 0; n < 2; ++n)
#pragma unroll
        for (int c = 0; c < 2; ++c)
          b[n][c] = *(const short8*)&lb[(wn * 32 + n * 16 + li) * 64 + (((c * 4 + hi) ^ (li & 7)) << 3)];

      if (z == 2) {   // V: normal orientation (acc rows = tokens)
#pragma unroll
        for (int m = 0; m < 4; ++m)
#pragma unroll
          for (int n = 0; n < 2; ++n)
#pragma unroll
            for (int c = 0; c < 2; ++c)
              acc[z][m][n] = __builtin_amdgcn_mfma_f32_16x16x32_bf16(a[m][c], b[n][c], acc[z][m][n], 0, 0, 0);
      } else {        // Q,K: swapped orientation (acc = C^T, rows = features)
#pragma unroll
        for (int m = 0; m < 4; ++m)
#pragma unroll
          for (int n = 0; n < 2; ++n)
#pragma unroll
            for (int c = 0; c < 2; ++c)
              acc[z][m][n] = __builtin_amdgcn_mfma_f32_16x16x32_bf16(b[n][c], a[m][c], acc[z][m][n], 0, 0, 0);
      }
    }

    if (i + 1 < 16) { asm volatile("s_waitcnt vmcnt(0)" ::: "memory"); }
    __builtin_amdgcn_s_barrier();
  }

  // ---- epilogue: Q,K scattered [B,H,T,HD] (uint2 of 4 d); V^T [B,H,HD,T] (uint2 of 4 t) ----
#pragma unroll
  for (int m = 0; m < 4; ++m)
#pragma unroll
    for (int n = 0; n < 2; ++n) {
      {  // z=0: Q (swapped, scale)
        int token = row0 + wm * 64 + m * 16 + li;
        int feat0 = col0 + wn * 32 + n * 16 + hi * 4;
        int b_ = token >> 11, t_ = token & (NT - 1);
        int h_ = feat0 >> 6,  d0 = feat0 & (NHD - 1);
        uint2 w;
        w.x = pk2bf(acc[0][m][n][0] * scl, acc[0][m][n][1] * scl);
        w.y = pk2bf(acc[0][m][n][2] * scl, acc[0][m][n][3] * scl);
        *(uint2*)&Qb[(((size_t)(b_ * NH + h_)) * NT + t_) * NHD + d0] = w;
      }
      {  // z=1: K (swapped)
        int token = row0 + wm * 64 + m * 16 + li;
        int feat0 = col0 + wn * 32 + n * 16 + hi * 4;
        int b_ = token >> 11, t_ = token & (NT - 1);
        int h_ = feat0 >> 6,  d0 = feat0 & (NHD - 1);
        uint2 w;
        w.x = pk2bf(acc[1][m][n][0], acc[1][m][n][1]);
        w.y = pk2bf(acc[1][m][n][2], acc[1][m][n][3]);
        *(uint2*)&Kb[(((size_t)(b_ * NH + h_)) * NT + t_) * NHD + d0] = w;
      }
      {  // z=2: V^T (normal)
        int token0 = row0 + wm * 64 + m * 16 + hi * 4;
        int col    = col0 + wn * 32 + n * 16 + li;
        int b_ = token0 >> 11, t0 = token0 & (NT - 1);
        int h_ = col >> 6,     d_ = col & (NHD - 1);
        uint2 w;
        w.x = pk2bf(acc[2][m][n][0], acc[2][m][n][1]);
        w.y = pk2bf(acc[2][m][n][2], acc[2][m][n][3]);
        *(uint2*)&VTb[(((size_t)(b_ * NH + h_)) * NHD + d_) * NT + t0] = w;
      }
    }
}

// ---------------- WO GEMM + residual, distance-2 triple-buffer pipeline (r14) ----------------
__global__ __launch_bounds__(512, 2) void gemm_wo3(
    const u16* __restrict__ ao, const u16* __restrict__ wob,
    const float* __restrict__ x, float* __restrict__ y) {
  const int row0 = blockIdx.x << 7;
  const int col0 = blockIdx.y << 7;

  const int tid  = threadIdx.x;
  const int lane = tid & 63, wid = tid >> 6;
  const int wm = wid >> 2, wn = wid & 3;
  const int li = lane & 15, hi = lane >> 4;
  const int l3 = lane >> 3, sl = lane & 7;
  const int schunk = ((sl ^ l3) << 3);

  extern __shared__ __align__(16) u16 smem[];
  u16* lAb = smem;
  u16* lBb = smem + 3 * 128 * 64;

  auto stage = [&](int t) {
    const int bo = (t % 3) * 8192;
    const int k0 = t << 6;
#pragma unroll
    for (int h = 0; h < 2; ++h) {
      int r = h * 64 + wid * 8;
      gll16(&ao [(size_t)(row0 + r + l3) * ND + k0 + schunk], &lAb[bo + r * 64]);
      gll16(&wob[(size_t)(col0 + r + l3) * ND + k0 + schunk], &lBb[bo + r * 64]);
    }
  };

  f32x4 acc[4][2] = {};

  stage(0);
  stage(1);

  for (int i = 0; i < 16; ++i) {
    if (i < 15) { asm volatile("s_waitcnt vmcnt(4)" ::: "memory"); }
    else        { asm volatile("s_waitcnt vmcnt(0)" ::: "memory"); }
    __builtin_amdgcn_s_barrier();

    if (i + 2 < 16) stage(i + 2);

    const u16* la = &lAb[(i % 3) * 8192];
    const u16* lb = &lBb[(i % 3) * 8192];

    short8 a[4][2], b[2][2];
#pragma unroll
    for (int m = 0; m < 4; ++m)
#pragma unroll
      for (int c = 0; c < 2; ++c)
        a[m][c] = *(const short8*)&la[(wm * 64 + m * 16 + li) * 64 + (((c * 4 + hi) ^ (li & 7)) << 3)];
#pragma unroll
    for (int n = 0; n < 2; ++n)
#pragma unroll
      for (int c = 0; c < 2; ++c)
        b[n][c] = *(const short8*)&lb[(wn * 32 + n * 16 + li) * 64 + (((c * 4 + hi) ^ (li & 7)) << 3)];

#pragma unroll
    for (int m = 0; m < 4; ++m)
#pragma unroll
      for (int n = 0; n < 2; ++n)
#pragma unroll
        for (int c = 0; c < 2; ++c)
          acc[m][n] = __builtin_amdgcn_mfma_f32_16x16x32_bf16(b[n][c], a[m][c], acc[m][n], 0, 0, 0);
  }

#pragma unroll
  for (int m = 0; m < 4; ++m)
#pragma unroll
    for (int n = 0; n < 2; ++n) {
      int token = row0 + wm * 64 + m * 16 + li;
      int feat0 = col0 + wn * 32 + n * 16 + hi * 4;
      size_t idx = (size_t)token * ND + feat0;
      float4 xv = *(const float4*)&x[idx];
      float4 o;
      o.x = acc[m][n][0] + xv.x; o.y = acc[m][n][1] + xv.y;
      o.z = acc[m][n][2] + xv.z; o.w = acc[m][n][3] + xv.w;
      *(float4*)&y[idx] = o;
    }
}

// ---------------- causal flash attention: deferred-PV pipeline (r16, 200.4us verified) -------
__global__ __launch_bounds__(256) void attn_kernel(
    const u16* __restrict__ Q, const u16* __restrict__ K, const u16* __restrict__ VT,
    u16* __restrict__ AO) {
  // T1: XCD-aware swizzle (2048 % 8 == 0 -> bijective)
  const int nb  = gridDim.x * gridDim.y;           // 2048
  const int b0  = blockIdx.y * gridDim.x + blockIdx.x;
  const int L   = (b0 & 7) * (nb >> 3) + (b0 >> 3);
  const int qb  = 31 - (L & 31);     // heavy-first: big qb dispatched early
  const int bh  = L >> 5;            // 0..63

  const int tid = threadIdx.x;
  const int lane = tid & 63, wid = tid >> 6;
  const int li = lane & 15, hi = lane >> 4;
  const int r0 = qb * 64 + wid * 16;         // wave's q rows
  const int qrow = r0 + li;                  // this lane's q row
  const size_t bK = (size_t)bh * NT * NHD;   // K  [bh][t][d]
  const size_t bV = (size_t)bh * NHD * NT;   // VT [bh][d][t]

  __shared__ __align__(16) u16 lK [2][64 * 64];
  __shared__ __align__(16) u16 lVT[3][64 * 64];
  __shared__ __align__(16) u16 lP [4][16 * 64];

  // reg-staging geometry: 512 chunks of 8 u16 per tile; thread owns ch0=tid, ch1=tid+256
  const int ch0 = tid, ch1 = tid + 256;
  const int d0 = (ch0 >> 3) * 64 + (((ch0 & 7) ^ ((ch0 >> 3) & 7)) << 3);
  const int d1 = (ch1 >> 3) * 64 + (((ch1 & 7) ^ ((ch1 >> 3) & 7)) << 3);
  const int vOff0 = (ch0 >> 3) * NT + (ch0 & 7) * 8;
  const int vOff1 = (ch1 >> 3) * NT + (ch1 & 7) * 8;

  uint4 gK0, gK1, gV0, gV1;
  auto issue = [&](int kt) {
    const u16* kp = K + bK + (size_t)kt * 4096;
    const u16* vp = VT + bV + kt * 64;
    gK0 = *(const uint4*)&kp[ch0 * 8];
    gK1 = *(const uint4*)&kp[ch1 * 8];
    gV0 = *(const uint4*)&vp[vOff0];
    gV1 = *(const uint4*)&vp[vOff1];
  };
  auto commit = [&](int kt) {          // K double-buffer (kt&1), V triple-buffer (kt%3)
    *(uint4*)&lK [kt & 1][d0] = gK0;
    *(uint4*)&lK [kt & 1][d1] = gK1;
    *(uint4*)&lVT[kt % 3][d0] = gV0;
    *(uint4*)&lVT[kt % 3][d1] = gV1;
  };

  // Q fragments (B-operand): lane holds Q[qrow][c*32 + hi*8 + e]
  short8 qf[2];
#pragma unroll
  for (int c = 0; c < 2; ++c)
    qf[c] = *(const short8*)&Q[bK + (size_t)qrow * NHD + c * 32 + hi * 8];

  short8 vone;
#pragma unroll
  for (int e = 0; e < 8; ++e) vone[e] = (short)0x3F80;   // bf16 1.0

  f32x4 o[4] = {};
  f32x4 o4 = {};             // rowsum accumulator (all 4 regs equal)
  short8 pap0, pap1;         // pa of previous tile (named scalars - no dyn indexing)

  issue(0);
  commit(0);
  __syncthreads();

  const int pswz = (li & 7) << 1;   // P-LDS XOR swizzle (8B chunks, bit0 preserved)

  for (int kt = 0; kt <= qb; ++kt) {
    if (kt < qb) issue(kt + 1);    // global loads in flight under the compute below

    // S^T = K Q^T from lK[kt&1]
    f32x4 s[4] = {};
    __builtin_amdgcn_s_setprio(1);
#pragma unroll
    for (int g = 0; g < 4; ++g)
#pragma unroll
      for (int c = 0; c < 2; ++c) {
        short8 kf = *(const short8*)&lK[kt & 1][(g * 16 + li) * 64 + ((c * 4 + hi) ^ (li & 7)) * 8];
        s[g] = __builtin_amdgcn_mfma_f32_16x16x32_bf16(kf, qf[c], s[g], 0, 0, 0);
      }

    // deferred PV(kt-1): independent of s -> fills QK's LDS-read shadow
    if (kt > 0) {
      const u16* lv = lVT[(kt - 1) % 3];
#pragma unroll
      for (int gd = 0; gd < 4; ++gd) {
        short8 vf0 = *(const short8*)&lv[(gd * 16 + li) * 64 + ((0 * 4 + hi) ^ (li & 7)) * 8];
        short8 vf1 = *(const short8*)&lv[(gd * 16 + li) * 64 + ((1 * 4 + hi) ^ (li & 7)) * 8];
        o[gd] = __builtin_amdgcn_mfma_f32_16x16x32_bf16(vf0, pap0, o[gd], 0, 0, 0);
        o[gd] = __builtin_amdgcn_mfma_f32_16x16x32_bf16(vf1, pap1, o[gd], 0, 0, 0);
      }
      o4 = __builtin_amdgcn_mfma_f32_16x16x32_bf16(vone, pap0, o4, 0, 0, 0);
      o4 = __builtin_amdgcn_mfma_f32_16x16x32_bf16(vone, pap1, o4, 0, 0, 0);
    }
    __builtin_amdgcn_s_setprio(0);

    if (kt == qb) {                          // causal mask on diagonal tile
#pragma unroll
      for (int g = 0; g < 4; ++g)
#pragma unroll
        for (int rg = 0; rg < 4; ++rg) {
          int kcol = kt * 64 + g * 16 + hi * 4 + rg;
          if (kcol > qrow) s[g][rg] = -INFINITY;
        }
    }

    // P = exp2(S) -> LDS as bf16 (static-max; exp2(-inf)=0 handles the mask)
#pragma unroll
    for (int g = 0; g < 4; ++g) {
      float p0 = __builtin_amdgcn_exp2f(s[g][0]);
      float p1 = __builtin_amdgcn_exp2f(s[g][1]);
      float p2 = __builtin_amdgcn_exp2f(s[g][2]);
      float p3 = __builtin_amdgcn_exp2f(s[g][3]);
      uint2 w;
      w.x = pk2bf(p0, p1);
      w.y = pk2bf(p2, p3);
      int k8s = (g * 4 + hi) ^ pswz;
      *(uint2*)&lP[wid][li * 64 + k8s * 4] = w;
    }

    // read pa(kt) (per-wave-private lP: lgkm-only dependency, drains under barrier)
    pap0 = *(const short8*)&lP[wid][li * 64 + ((0 * 8 + hi * 2) ^ pswz) * 4];
    pap1 = *(const short8*)&lP[wid][li * 64 + ((1 * 8 + hi * 2) ^ pswz) * 4];

    if (kt < qb) commit(kt + 1);   // vmcnt consumed here (hidden under compute above)
    __syncthreads();
  }

  // final PV(qb)
  {
    const u16* lv = lVT[qb % 3];
#pragma unroll
    for (int gd = 0; gd < 4; ++gd) {
      short8 vf0 = *(const short8*)&lv[(gd * 16 + li) * 64 + ((0 * 4 + hi) ^ (li & 7)) * 8];
      short8 vf1 = *(const short8*)&lv[(gd * 16 + li) * 64 + ((1 * 4 + hi) ^ (li & 7)) * 8];
      o[gd] = __builtin_amdgcn_mfma_f32_16x16x32_bf16(vf0, pap0, o[gd], 0, 0, 0);
      o[gd] = __builtin_amdgcn_mfma_f32_16x16x32_bf16(vf1, pap1, o[gd], 0, 0, 0);
    }
    o4 = __builtin_amdgcn_mfma_f32_16x16x32_bf16(vone, pap0, o4, 0, 0, 0);
    o4 = __builtin_amdgcn_mfma_f32_16x16x32_bf16(vone, pap1, o4, 0, 0, 0);
  }

  // epilogue: O /= rowsum; pack 4 bf16 (8B) per gd and store
  const int b_ = bh >> 4, h_ = bh & 15;
  const float inv = 1.0f / o4[0];
  const size_t rowbase = ((size_t)(b_ * NT + qrow)) * ND + h_ * 64;
#pragma unroll
  for (int gd = 0; gd < 4; ++gd) {
    uint2 w;
    w.x = pk2bf(o[gd][0] * inv, o[gd][1] * inv);
    w.y = pk2bf(o[gd][2] * inv, o[gd][3] * inv);
    *(uint2*)&AO[rowbase + gd * 16 + hi * 4] = w;
  }
}

// ---------------- RMSNorm in-place on d_out ----------------
__global__ __launch_bounds__(256) void rmsnorm_kernel(float* __restrict__ y,
                                                      const float* __restrict__ g) {
  const int row = blockIdx.x;
  const int tid = threadIdx.x;
  const int lane = tid & 63, wid = tid >> 6;
  float4 v = ((const float4*)(y + (size_t)row * ND))[tid];
  float ss = v.x * v.x + v.y * v.y + v.z * v.z + v.w * v.w;
#pragma unroll
  for (int off = 32; off; off >>= 1) ss += __shfl_down(ss, off);
  __shared__ float red[4];
  if (lane == 0) red[wid] = ss;
  __syncthreads();
  float tot = red[0] + red[1] + red[2] + red[3];
  float inv = rsqrtf(tot * (1.0f / (float)ND) + 1e-6f);
  float4 gg = ((const float4*)g)[tid];
  float4 o;
  o.x = v.x * inv * gg.x; o.y = v.y * inv * gg.y;
  o.z = v.z * inv * gg.z; o.w = v.w * inv * gg.w;
  ((float4*)(y + (size_t)row * ND))[tid] = o;
}

extern "C" void kernel_launch(void* const* d_in, const int* in_sizes, int n_in,
                              void* d_out, int out_size, void* d_ws, size_t ws_size,
                              hipStream_t stream) {
  const float* x  = (const float*)d_in[0];
  const float* wq = (const float*)d_in[1];
  const float* wk = (const float*)d_in[2];
  const float* wv = (const float*)d_in[3];
  const float* wo = (const float*)d_in[4];
  const float* ng = (const float*)d_in[5];
  float* out = (float*)d_out;

  char* ws = (char*)d_ws;
  u16* xb  = (u16*)(ws);                    // 16 MB  [M, D] bf16
  u16* wqb = (u16*)(ws + (16u << 20));      //  2 MB
  u16* wkb = (u16*)(ws + (18u << 20));
  u16* wvb = (u16*)(ws + (20u << 20));
  u16* wob = (u16*)(ws + (22u << 20));
  u16* Qb  = (u16*)(ws + (24u << 20));      // 16 MB  [B,H,T,HD]
  u16* Kb  = (u16*)(ws + (40u << 20));      // 16 MB  [B,H,T,HD]
  u16* VTb = (u16*)(ws + (56u << 20));      // 16 MB  [B,H,HD,T]  (transposed V)
  u16* AO  = (u16*)(ws + (72u << 20));      // 16 MB  [M, D]  (ends at 88 MB)

  cast_all<<<8192 + 4096, 256, 0, stream>>>(x, wq, wk, wv, wo, xb, wqb, wkb, wvb, wob);

  gemm_qkvm<<<dim3(64, 8), 512, 131072, stream>>>(xb, wqb, wkb, wvb, Qb, Kb, VTb);
  attn_kernel<<<dim3(NT / 64, NB * NH), 256, 0, stream>>>(Qb, Kb, VTb, AO);
  gemm_wo3<<<dim3(64, 8), 512, 98304, stream>>>(AO, wob, x, out);
  rmsnorm_kernel<<<NM, 256, 0, stream>>>(out, ng);
}